// Round 14
// baseline (428.473 us; speedup 1.0000x reference)
//
#include <hip/hip_runtime.h>
#include <stdint.h>
#include <math.h>

typedef unsigned short u16;
typedef __bf16 bf16x8 __attribute__((ext_vector_type(8)));
typedef _Float16 f16x8 __attribute__((ext_vector_type(8)));
typedef float f32x4 __attribute__((ext_vector_type(4)));

__device__ __forceinline__ u16 f32_bf16_rn(float f) {
  uint32_t u = __float_as_uint(f);
  uint32_t r = (u + 0x7FFFu + ((u >> 16) & 1u)) >> 16;
  return (u16)r;
}
__device__ __forceinline__ float bf16_f32(u16 h) {
  return __uint_as_float(((uint32_t)h) << 16);
}
__device__ __forceinline__ u16 f16_bits(_Float16 h) {
  return __builtin_bit_cast(unsigned short, h);
}

// async global->LDS, 16B per lane. LDS dest = wave-uniform base + lane*16.
__device__ __forceinline__ void async16(const u16* g, u16* l) {
  __builtin_amdgcn_global_load_lds(
      (__attribute__((address_space(1))) void*)(g),
      (__attribute__((address_space(3))) void*)(l), 16, 0, 0);
}

// ---------------------------------------------------------------------------
// prep2: fused prep + tr_split.
// blocks [0,1024): x -> x2f f16 h|l; Wqkv[4096:6144] -> Wvf f16; Wproj -> Wp.
// blocks [1024,9216): transposed splits WqTf (f16 h|l) / WkTf (f16).
// ---------------------------------------------------------------------------
__global__ __launch_bounds__(256)
void prep2(const float* __restrict__ x, const float* __restrict__ Wqkv,
           const float* __restrict__ Wproj,
           u16* __restrict__ x2f, u16* __restrict__ Wvf, u16* __restrict__ Wp,
           u16* __restrict__ WqTf, u16* __restrict__ WkTf) {
  const int bid = blockIdx.x;
  const int tid = threadIdx.x;
  if (bid < 1024) {
    const int stride = 1024 * 256;
    const int tid0 = bid * 256 + tid;
    {
      const float4* in4 = (const float4*)x;
      const int total4 = 4096 * 512;
      for (int i = tid0; i < total4; i += stride) {
        int r = i >> 9, c4 = i & 511;
        float4 f = in4[i];
        ushort4 h, l;
        _Float16 t;
        t = (_Float16)f.x; h.x = f16_bits(t); l.x = f16_bits((_Float16)(f.x - (float)t));
        t = (_Float16)f.y; h.y = f16_bits(t); l.y = f16_bits((_Float16)(f.y - (float)t));
        t = (_Float16)f.z; h.z = f16_bits(t); l.z = f16_bits((_Float16)(f.z - (float)t));
        t = (_Float16)f.w; h.w = f16_bits(t); l.w = f16_bits((_Float16)(f.w - (float)t));
        *(ushort4*)&x2f[(size_t)r * 4096 + c4 * 4] = h;
        *(ushort4*)&x2f[(size_t)r * 4096 + 2048 + c4 * 4] = l;
      }
    }
    {
      const float4* in4 = (const float4*)(Wqkv + (size_t)4096 * 2048);
      const int total4 = 2048 * 512;
      for (int i = tid0; i < total4; i += stride) {
        float4 f = in4[i];
        ushort4 o;
        o.x = f16_bits((_Float16)f.x); o.y = f16_bits((_Float16)f.y);
        o.z = f16_bits((_Float16)f.z); o.w = f16_bits((_Float16)f.w);
        ((ushort4*)Wvf)[i] = o;
      }
    }
    {
      const float4* in4 = (const float4*)Wproj;
      const int total4 = 2048 * 512;
      for (int i = tid0; i < total4; i += stride) {
        float4 f = in4[i];
        ushort4 o;
        o.x = f32_bf16_rn(f.x); o.y = f32_bf16_rn(f.y);
        o.z = f32_bf16_rn(f.z); o.w = f32_bf16_rn(f.w);
        ((ushort4*)Wp)[i] = o;
      }
    }
  } else {
    __shared__ float tile[32][33];
    const int b = bid - 1024;
    const int z = b >> 12;             // 0: Wq, 1: Wk
    const int b2 = b & 4095;
    const int d0 = (b2 & 63) * 32, i0 = (b2 >> 6) * 32;
    const int tx = tid & 31, ty = tid >> 5;   // (32,8)
    const float* in = Wqkv + (size_t)z * 2048 * 2048;
#pragma unroll
    for (int j = 0; j < 32; j += 8)
      tile[ty + j][tx] = in[(size_t)(i0 + ty + j) * 2048 + d0 + tx];
    __syncthreads();
#pragma unroll
    for (int j = 0; j < 32; j += 8) {
      float v = tile[tx][ty + j];             // = W[i0+tx][d0+ty+j]
      if (z == 0) {
        _Float16 th = (_Float16)v;
        _Float16 tl = (_Float16)(v - (float)th);
        size_t ro = (size_t)(d0 + ty + j) * 4096;
        WqTf[ro + i0 + tx] = f16_bits(th);
        WqTf[ro + 2048 + i0 + tx] = f16_bits(tl);
      } else {
        WkTf[(size_t)(d0 + ty + j) * 2048 + i0 + tx] = f16_bits((_Float16)v);
      }
    }
  }
}

// ---------------------------------------------------------------------------
// single-pass causal row softmax on SCALED logits (s = 256*S).
// Paired grid: block b handles rows b and 4095-b (uniform work).
// ---------------------------------------------------------------------------
__device__ __forceinline__ float waveMax(float v) {
#pragma unroll
  for (int o = 32; o > 0; o >>= 1) v = fmaxf(v, __shfl_xor(v, o));
  return v;
}
__device__ __forceinline__ float waveSum(float v) {
#pragma unroll
  for (int o = 32; o > 0; o >>= 1) v += __shfl_xor(v, o);
  return v;
}

__device__ __forceinline__
void sm_row(int row, const float* __restrict__ S, u16* __restrict__ P,
            float* __restrict__ inv, int L, float* sred) {
  const int tid = threadIdx.x;
  const int wave = tid >> 6, lane = tid & 63;
  const int n = row + 1;
  const int pad4 = (((row >> 7) + 1) << 7) >> 2;
  const float4* s4 = (const float4*)(S + (size_t)row * L);
  const float SC = 1.0f / 256.0f;

  float4 v[4];
  float m = -3.4e38f;
#pragma unroll
  for (int c = 0; c < 4; ++c) {
    int j4 = tid + c * 256;
    if (j4 < pad4) {
      v[c] = s4[j4];
      int jb = j4 * 4;
      m = fmaxf(m, (jb + 0 < n) ? v[c].x : -3.4e38f);
      m = fmaxf(m, (jb + 1 < n) ? v[c].y : -3.4e38f);
      m = fmaxf(m, (jb + 2 < n) ? v[c].z : -3.4e38f);
      m = fmaxf(m, (jb + 3 < n) ? v[c].w : -3.4e38f);
    }
  }
  m = waveMax(m);
  if (lane == 0) sred[wave] = m;
  __syncthreads();
  m = fmaxf(fmaxf(sred[0], sred[1]), fmaxf(sred[2], sred[3]));

  u16* p = P + (size_t)row * L;
  float sum = 0.0f;
#pragma unroll
  for (int c = 0; c < 4; ++c) {
    int j4 = tid + c * 256;
    if (j4 < pad4) {
      int jb = j4 * 4;
      float e0 = (jb + 0 < n) ? __expf((v[c].x - m) * SC) : 0.0f;
      float e1 = (jb + 1 < n) ? __expf((v[c].y - m) * SC) : 0.0f;
      float e2 = (jb + 2 < n) ? __expf((v[c].z - m) * SC) : 0.0f;
      float e3 = (jb + 3 < n) ? __expf((v[c].w - m) * SC) : 0.0f;
      ushort4 o;
      o.x = f32_bf16_rn(e0); o.y = f32_bf16_rn(e1);
      o.z = f32_bf16_rn(e2); o.w = f32_bf16_rn(e3);
      *(ushort4*)&p[jb] = o;
      sum += e0 + e1 + e2 + e3;
    }
  }
  sum = waveSum(sum);
  if (lane == 0) sred[4 + wave] = sum;
  __syncthreads();
  if (tid == 0) inv[row] = 1.0f / (sred[4] + sred[5] + sred[6] + sred[7]);
}

__global__ __launch_bounds__(256)
void softmax1p(const float* __restrict__ S, u16* __restrict__ P,
               float* __restrict__ inv, int L) {
  __shared__ float sred[8];
  sm_row(blockIdx.x, S, P, inv, L, sred);
  __syncthreads();
  sm_row(4095 - blockIdx.x, S, P, inv, L, sred);
}

// ---------------------------------------------------------------------------
// shared epilogue (acc layout: col = lane&15, row = (lane>>4)*4 + r).
// EPI 0: f32 C (+bias). EPI 2: vT transposed bf16 (+bias).
// EPI 3: bf16 row-major, row-scale inv[]. EPI 4: f16 x256 hi/lo split (T).
// EPI 5: f16 single row-major (M).
// ---------------------------------------------------------------------------
template<int EPI, bool HAS_BIAS>
__device__ __forceinline__
void epi_store(f32x4 (&acc)[4][4], float* __restrict__ Cf, u16* __restrict__ o16,
               int ldc, const float* __restrict__ bias,
               const float* __restrict__ inv, int bx, int by) {
  const int tid = threadIdx.x;
  const int wave = tid >> 6, lane = tid & 63;
  const int wr = wave >> 1, wc = wave & 1;
  const int fcol = lane & 15;
  const int r0 = by * 128 + wr * 64 + ((lane >> 4) << 2);

  if (EPI == 0) {
#pragma unroll
    for (int mi = 0; mi < 4; ++mi)
#pragma unroll
      for (int ni = 0; ni < 4; ++ni) {
        int cc = bx * 128 + wc * 64 + ni * 16 + fcol;
        float bv = HAS_BIAS ? bias[cc] : 0.0f;
#pragma unroll
        for (int r = 0; r < 4; ++r)
          Cf[(size_t)(r0 + mi * 16 + r) * ldc + cc] = acc[mi][ni][r] + bv;
      }
  } else if (EPI == 2) {
#pragma unroll
    for (int mi = 0; mi < 4; ++mi)
#pragma unroll
      for (int ni = 0; ni < 4; ++ni) {
        const int vc = bx * 128 + wc * 64 + ni * 16 + fcol;
        const float bv = HAS_BIAS ? bias[vc] : 0.0f;
        ushort4 o;
        o.x = f32_bf16_rn(acc[mi][ni][0] + bv);
        o.y = f32_bf16_rn(acc[mi][ni][1] + bv);
        o.z = f32_bf16_rn(acc[mi][ni][2] + bv);
        o.w = f32_bf16_rn(acc[mi][ni][3] + bv);
        *(ushort4*)&o16[(size_t)vc * 4096 + r0 + mi * 16] = o;
      }
  } else if (EPI == 3) {
#pragma unroll
    for (int mi = 0; mi < 4; ++mi)
#pragma unroll
      for (int ni = 0; ni < 4; ++ni) {
        int cc = bx * 128 + wc * 64 + ni * 16 + fcol;
#pragma unroll
        for (int r = 0; r < 4; ++r) {
          int rr = r0 + mi * 16 + r;
          o16[(size_t)rr * ldc + cc] = f32_bf16_rn(acc[mi][ni][r] * inv[rr]);
        }
      }
  } else if (EPI == 4) {
#pragma unroll
    for (int mi = 0; mi < 4; ++mi)
#pragma unroll
      for (int ni = 0; ni < 4; ++ni) {
        const int cc = bx * 128 + wc * 64 + ni * 16 + fcol;
#pragma unroll
        for (int r = 0; r < 4; ++r) {
          float a = acc[mi][ni][r] * 256.0f;
          _Float16 th = (_Float16)a;
          _Float16 tl = (_Float16)(a - (float)th);
          size_t ro = (size_t)(r0 + mi * 16 + r) * 4096;
          o16[ro + cc] = f16_bits(th);
          o16[ro + 2048 + cc] = f16_bits(tl);
        }
      }
  } else {
#pragma unroll
    for (int mi = 0; mi < 4; ++mi)
#pragma unroll
      for (int ni = 0; ni < 4; ++ni) {
        int cc = bx * 128 + wc * 64 + ni * 16 + fcol;
#pragma unroll
        for (int r = 0; r < 4; ++r)
          o16[(size_t)(r0 + mi * 16 + r) * ldc + cc] =
              f16_bits((_Float16)acc[mi][ni][r]);
      }
  }
}

// ---------------------------------------------------------------------------
// gemm_body: 128x128 NT GEMM (proven m97 structure), BK=64, single operandA.
// Used for v (f16), PV and out (bf16). CAUSAL 2: Keff = by*128+128.
// ---------------------------------------------------------------------------
template<int EPI, int CAUSAL, bool HAS_BIAS, int DT>
__device__ __forceinline__
void gemm_body(const u16* __restrict__ A, int lda, const u16* __restrict__ B, int ldb,
               float* __restrict__ Cf, u16* __restrict__ o16, int ldc,
               const float* __restrict__ bias, const float* __restrict__ inv,
               int K, int bx, int by, u16* As, u16* Bs) {
  constexpr int BK = 64;
  const int Keff = (CAUSAL == 2) ? (by * 128 + 128) : K;

  const int tid = threadIdx.x;
  const int wave = tid >> 6, lane = tid & 63;
  const int wr = wave >> 1, wc = wave & 1;

  const int srow = lane >> 3;
  const int scol = ((lane & 7) ^ srow) << 3;
  const u16* Ag = A + (size_t)(by * 128 + wave * 8 + srow) * lda + scol;
  const u16* Bg = B + (size_t)(bx * 128 + wave * 8 + srow) * ldb + scol;
  u16* AsW = As + wave * 8 * BK;
  u16* BsW = Bs + wave * 8 * BK;

  f32x4 acc[4][4];
#pragma unroll
  for (int i = 0; i < 4; ++i)
#pragma unroll
    for (int j = 0; j < 4; ++j) acc[i][j] = (f32x4){0.f, 0.f, 0.f, 0.f};

  for (int k0 = 0; k0 < Keff; k0 += BK) {
#pragma unroll
    for (int it = 0; it < 4; ++it) {
      async16(Ag + (size_t)it * 32 * lda + k0, AsW + it * 32 * BK);
      async16(Bg + (size_t)it * 32 * ldb + k0, BsW + it * 32 * BK);
    }
    __syncthreads();

#pragma unroll
    for (int kk = 0; kk < 2; ++kk) {
      bf16x8 af[4], bb[4];
      int col = lane & 15;
      int sl = kk * 4 + (lane >> 4);
#pragma unroll
      for (int mi = 0; mi < 4; ++mi) {
        int row = wr * 64 + mi * 16 + col;
        af[mi] = *(const bf16x8*)&As[row * BK + ((sl ^ (row & 7)) << 3)];
      }
#pragma unroll
      for (int ni = 0; ni < 4; ++ni) {
        int row = wc * 64 + ni * 16 + col;
        bb[ni] = *(const bf16x8*)&Bs[row * BK + ((sl ^ (row & 7)) << 3)];
      }
#pragma unroll
      for (int mi = 0; mi < 4; ++mi)
#pragma unroll
        for (int ni = 0; ni < 4; ++ni) {
          if constexpr (DT == 0) {
            acc[mi][ni] = __builtin_amdgcn_mfma_f32_16x16x32_bf16(
                af[mi], bb[ni], acc[mi][ni], 0, 0, 0);
          } else {
            acc[mi][ni] = __builtin_amdgcn_mfma_f32_16x16x32_f16(
                __builtin_bit_cast(f16x8, af[mi]), __builtin_bit_cast(f16x8, bb[ni]),
                acc[mi][ni], 0, 0, 0);
          }
        }
    }
    __syncthreads();
  }
  epi_store<EPI, HAS_BIAS>(acc, Cf, o16, ldc, bias, inv, bx, by);
}

// ---------------------------------------------------------------------------
// gemm2_body: limb-merged 2-term f16 GEMM. A = [hi|lo] (lda 4096), B single.
// Per 64-wide d-tile: stage Ah/Al/B (48 KB LDS), 64 f16 MFMAs (both limbs
// vs one B tile) between one barrier pair. D = 2048 logical dot length.
// ---------------------------------------------------------------------------
template<int EPI, bool HAS_BIAS>
__device__ __forceinline__
void gemm2_body(const u16* __restrict__ A, int lda, const u16* __restrict__ B, int ldb,
                float* __restrict__ Cf, u16* __restrict__ o16, int ldc,
                const float* __restrict__ bias, const float* __restrict__ inv,
                int D, int bx, int by, u16* Ah, u16* Al, u16* Bs) {
  const int tid = threadIdx.x;
  const int wave = tid >> 6, lane = tid & 63;
  const int wr = wave >> 1, wc = wave & 1;

  const int srow = lane >> 3;
  const int scol = ((lane & 7) ^ srow) << 3;
  const u16* Agh = A + (size_t)(by * 128 + wave * 8 + srow) * lda + scol;
  const u16* Agl = Agh + 2048;
  const u16* Bg = B + (size_t)(bx * 128 + wave * 8 + srow) * ldb + scol;
  u16* AhW = Ah + wave * 8 * 64;
  u16* AlW = Al + wave * 8 * 64;
  u16* BsW = Bs + wave * 8 * 64;

  f32x4 acc[4][4];
#pragma unroll
  for (int i = 0; i < 4; ++i)
#pragma unroll
    for (int j = 0; j < 4; ++j) acc[i][j] = (f32x4){0.f, 0.f, 0.f, 0.f};

  for (int d0 = 0; d0 < D; d0 += 64) {
#pragma unroll
    for (int it = 0; it < 4; ++it) {
      async16(Agh + (size_t)it * 32 * lda + d0, AhW + it * 32 * 64);
      async16(Agl + (size_t)it * 32 * lda + d0, AlW + it * 32 * 64);
      async16(Bg + (size_t)it * 32 * ldb + d0, BsW + it * 32 * 64);
    }
    __syncthreads();

#pragma unroll
    for (int kk = 0; kk < 2; ++kk) {
      bf16x8 ah[4], al[4], bb[4];
      int col = lane & 15;
      int sl = kk * 4 + (lane >> 4);
#pragma unroll
      for (int ni = 0; ni < 4; ++ni) {
        int row = wc * 64 + ni * 16 + col;
        bb[ni] = *(const bf16x8*)&Bs[row * 64 + ((sl ^ (row & 7)) << 3)];
      }
#pragma unroll
      for (int mi = 0; mi < 4; ++mi) {
        int row = wr * 64 + mi * 16 + col;
        ah[mi] = *(const bf16x8*)&Ah[row * 64 + ((sl ^ (row & 7)) << 3)];
      }
#pragma unroll
      for (int mi = 0; mi < 4; ++mi)
#pragma unroll
        for (int ni = 0; ni < 4; ++ni)
          acc[mi][ni] = __builtin_amdgcn_mfma_f32_16x16x32_f16(
              __builtin_bit_cast(f16x8, ah[mi]), __builtin_bit_cast(f16x8, bb[ni]),
              acc[mi][ni], 0, 0, 0);
#pragma unroll
      for (int mi = 0; mi < 4; ++mi) {
        int row = wr * 64 + mi * 16 + col;
        al[mi] = *(const bf16x8*)&Al[row * 64 + ((sl ^ (row & 7)) << 3)];
      }
#pragma unroll
      for (int mi = 0; mi < 4; ++mi)
#pragma unroll
        for (int ni = 0; ni < 4; ++ni)
          acc[mi][ni] = __builtin_amdgcn_mfma_f32_16x16x32_f16(
              __builtin_bit_cast(f16x8, al[mi]), __builtin_bit_cast(f16x8, bb[ni]),
              acc[mi][ni], 0, 0, 0);
    }
    __syncthreads();
  }
  epi_store<EPI, HAS_BIAS>(acc, Cf, o16, ldc, bias, inv, bx, by);
}

// ---------------------------------------------------------------------------
// wrappers
// GRID 0: bx=s%nxb, by=s/nxb. GRID 1: triangular bx<=by.
// GRID 3: PV paired long/short (nxb=16, NY=32): s<256 pairs with s+256.
// ---------------------------------------------------------------------------
template<int EPI, bool HAS_BIAS, int GRID>
__global__ __launch_bounds__(256)
void gemm2_u(const u16* __restrict__ A, int lda, const u16* __restrict__ B, int ldb,
             float* __restrict__ Cf, u16* __restrict__ o16, int ldc,
             const float* __restrict__ bias, const float* __restrict__ inv,
             int D, int nxb) {
  __shared__ u16 Ah[128 * 64];
  __shared__ u16 Al[128 * 64];
  __shared__ u16 Bs[128 * 64];
  const int s = blockIdx.x;
  int bx, by;
  if (GRID == 1) {
    by = (int)((sqrtf(8.0f * (float)s + 1.0f) - 1.0f) * 0.5f);
    while ((by + 1) * (by + 2) / 2 <= s) ++by;
    while (by * (by + 1) / 2 > s) --by;
    bx = s - by * (by + 1) / 2;
  } else {
    bx = s % nxb;
    by = s / nxb;
  }
  gemm2_body<EPI, HAS_BIAS>(A, lda, B, ldb, Cf, o16, ldc, bias, inv, D, bx, by,
                            Ah, Al, Bs);
}

template<int EPI, int CAUSAL, bool HAS_BIAS, int GRID, int DT>
__global__ __launch_bounds__(256)
void gemm_u(const u16* __restrict__ A, int lda, const u16* __restrict__ B, int ldb,
            float* __restrict__ Cf, u16* __restrict__ o16, int ldc,
            const float* __restrict__ bias, const float* __restrict__ inv,
            int K, int nxb) {
  __shared__ u16 As[128 * 64];
  __shared__ u16 Bs[128 * 64];
  const int s = blockIdx.x;
  int bx, by;
  if (GRID == 3) {
    // paired long/short: block s and s+256 land on the same CU slot pattern;
    // Keff sums to a uniform 33 tiles per pair.
    if (s < 256) { bx = s & 15; by = 31 - (s >> 4); }
    else         { bx = (s - 256) & 15; by = (s - 256) >> 4; }
  } else {
    bx = s % nxb;
    by = s / nxb;
  }
  gemm_body<EPI, CAUSAL, HAS_BIAS, DT>(
      A, lda, B, ldb, Cf, o16, ldc, bias, inv, K, bx, by, As, Bs);
}

// ---------------------------------------------------------------------------
// fused M + v launch: blocks [0,256) = M (limb-merged, D=2048, f16 out),
// blocks [256,768) = v-proj (f16 single) -> vT transposed (+bias).
// ---------------------------------------------------------------------------
__global__ __launch_bounds__(256)
void gemm_mv(const u16* __restrict__ WqTf, const u16* __restrict__ WkTf,
             u16* __restrict__ Mf,
             const u16* __restrict__ x2f, const u16* __restrict__ Wvf,
             u16* __restrict__ vT, const float* __restrict__ bias_v) {
  __shared__ u16 L0[128 * 64];
  __shared__ u16 L1[128 * 64];
  __shared__ u16 L2[128 * 64];
  const int bid = blockIdx.x;
  if (bid < 256) {
    const int bx = bid & 15, by = bid >> 4;
    gemm2_body<5, false>(WqTf, 4096, WkTf, 2048, nullptr, Mf, 2048,
                         nullptr, nullptr, 2048, bx, by, L0, L1, L2);
  } else {
    const int s = bid - 256;
    const int bx = s & 15, by = s >> 4;
    gemm_body<2, 0, true, 1>(x2f, 4096, Wvf, 2048, nullptr, vT, 0,
                             bias_v, nullptr, 2048, bx, by, L0, L2);
  }
}

// ---------------------------------------------------------------------------
extern "C" void kernel_launch(void* const* d_in, const int* in_sizes, int n_in,
                              void* d_out, int out_size, void* d_ws, size_t ws_size,
                              hipStream_t stream) {
  (void)in_sizes; (void)n_in; (void)out_size; (void)ws_size;
  const float* x     = (const float*)d_in[0];  // [4096][2048]
  const float* Wqkv  = (const float*)d_in[1];  // [6144][2048]
  const float* bqkv  = (const float*)d_in[2];  // [6144]
  const float* Wproj = (const float*)d_in[3];  // [2048][2048]
  const float* bproj = (const float*)d_in[4];  // [2048]
  float* out = (float*)d_out;                  // [4096][2048]

  char* w = (char*)d_ws;
  u16*   x2f  = (u16*)w;                       // [4096][4096] x f16 h|l   @0       (dies after S)
  u16*   WqTf = (u16*)(w + 33554432);          // [2048][4096] Wq^T f16 h|l         (dies after M)
  u16*   WkTf = (u16*)(w + 50331648);          // [2048][2048] Wk^T f16             (dies after M)
  u16*   T2f  = (u16*)(w + 33554432);          // [4096][4096] T f16 h|l x256 (over WqTf/WkTf)
  u16*   Mf   = (u16*)(w + 67108864);          // [2048][2048] M^T f16              (dies after T)
  u16*   vT   = (u16*)(w + 75497472);          // [2048][4096] v^T bf16
  u16*   Wvf  = (u16*)(w + 92274688);          // [2048][2048] f16                  (dies after v)
  u16*   Wp   = (u16*)(w + 100663296);         // [2048][2048] bf16
  float* Smat = (float*)(w + 109051904);       // [4096][4096] f32
  float* inv  = (float*)(w + 67108864);        // [4096] f32 (over Mf, dead after T)
  u16*   P    = (u16*)w;                       // [4096][4096] bf16 (over x2f, dead)
  u16*   ao   = (u16*)(w + 33554432);          // [4096][2048] bf16 (over T2f, dead)

  // 1) fused prep + transposed splits
  prep2<<<9216, 256, 0, stream>>>(x, Wqkv, Wproj, x2f, Wvf, Wp, WqTf, WkTf);

  // 2) fused: M^T = Wq^T @ Wk (limb-merged) + v-proj -> vT
  gemm_mv<<<768, 256, 0, stream>>>(WqTf, WkTf, Mf, x2f, Wvf, vT, bqkv + 4096);

  // 3) T = x @ M^T (limb-merged, D=2048) -> T2f f16 h|l x256
  gemm2_u<4, false, 0><<<512, 256, 0, stream>>>(
      x2f, 4096, Mf, 2048, nullptr, T2f, 0, nullptr, nullptr, 2048, 16);

  // 4) S*256 = T2f @ xh^T (limb-merged, D=2048, triangular) -> f32
  gemm2_u<0, false, 1><<<528, 256, 0, stream>>>(
      T2f, 4096, x2f, 4096, Smat, nullptr, 4096, nullptr, nullptr, 2048, 32);

  // 5) softmax (scaled logits /256), paired rows -> P + inv[]
  softmax1p<<<2048, 256, 0, stream>>>(Smat, P, inv, 4096);

  // 6) attn = (P @ v) * inv[row]  (Keff=(by+1)*128, paired long/short) -> bf16
  gemm_u<3, 2, false, 3, 0><<<512, 256, 0, stream>>>(
      P, 4096, vT, 4096, nullptr, ao, 2048, nullptr, inv, 4096, 16);

  // 7) out = attn @ Wproj^T + bproj -> f32
  gemm_u<0, 0, true, 0, 0><<<512, 256, 0, stream>>>(
      ao, 2048, Wp, 2048, out, nullptr, 2048, bproj, nullptr, 2048, 16);
}